// Round 4
// baseline (1159.617 us; speedup 1.0000x reference)
//
#include <hip/hip_runtime.h>
#include <stdint.h>

typedef __attribute__((ext_vector_type(8))) short bf16x8;
typedef __attribute__((ext_vector_type(4))) short bf16x4;
typedef __attribute__((ext_vector_type(4))) float f32x4;

#define DEV static __device__ __forceinline__

DEV float bf2f(short u) {
    union { float f; uint32_t i; } v;
    v.i = ((uint32_t)(uint16_t)u) << 16;
    return v.f;
}
DEV short f2bf(float f) {
    union { float f; uint32_t i; } v; v.f = f;
    uint32_t r = v.i + 0x7fff + ((v.i >> 16) & 1);
    return (short)(r >> 16);
}

DEV void gload_lds16(const void* g, void* l) {
    __builtin_amdgcn_global_load_lds(
        (__attribute__((address_space(1))) void*)(void*)g,
        (__attribute__((address_space(3))) void*)l,
        16, 0, 0);
}

// ---------------- f32 -> bf16 conversion ----------------
__global__ __launch_bounds__(256) void cvt_kernel(const float* __restrict__ in,
                                                  ushort* __restrict__ out, int n4) {
    int idx = blockIdx.x * 256 + threadIdx.x;
    int stride = gridDim.x * 256;
    for (int i = idx; i < n4; i += stride) {
        float4 v = ((const float4*)in)[i];
        bf16x4 o;
        o.x = f2bf(v.x); o.y = f2bf(v.y); o.z = f2bf(v.z); o.w = f2bf(v.w);
        ((bf16x4*)out)[i] = o;
    }
}

// ============ 256x256 8-wave GEMM, 4-phase/K-tile schedule ============
// C[m,n] = epi(sum_k A[m,k]*Bw[n,k] + bias[n]), batched over blockIdx.z.
// BK=64, double-buffered LDS (128 KiB), K-major conflict-free layout
// [kchunk(8)][row(256)][8 ushorts].  Per phase: 8 ds_read_b128 + 16 MFMA,
// barrier-paired; all 8 global_load_lds for tile t+1 issued in phase 0;
// vmcnt(0) only at end of phase 3 (loads then ~3 phases old).
// MODE 0: relu(acc+bias) -> bf16 ;  MODE 1: acc+bias -> bf16
template<int MODE>
__global__ __launch_bounds__(512) void gemm256(
    const ushort* __restrict__ A,
    const ushort* __restrict__ Bw,
    const float* __restrict__ bias,
    ushort* __restrict__ Cb,
    int M, int N, int K,
    long sA, long sB, long sBias, long sC)
{
    __shared__ ushort lA[2][16384];   // 2 bufs x 32 KB
    __shared__ ushort lB[2][16384];

    const int z = blockIdx.z;
    const ushort* Az = A + (size_t)z * sA;
    const ushort* Bz = Bw + (size_t)z * sB;
    const float*  bz = bias + (size_t)z * sBias;
    ushort*       Cz = Cb + (size_t)z * sC;

    const int tid  = threadIdx.x;
    const int lane = tid & 63;
    const int wid  = tid >> 6;        // 0..7
    const int wr   = wid >> 2;        // 0..1  (128 rows)
    const int wc   = wid & 3;         // 0..3  (64 cols)
    const int fr   = lane & 15;
    const int hi   = lane >> 4;       // 0..3
    const int m0   = blockIdx.x * 256;
    const int n0   = blockIdx.y * 256;

    // staging: chunk c = p*512 + wid*64 + lane; row = c&255, kchunk = c>>8
    int rs[4], kcs[4];
#pragma unroll
    for (int p = 0; p < 4; p++) {
        const int c = p * 512 + wid * 64 + lane;
        rs[p] = c & 255; kcs[p] = c >> 8;
    }

    f32x4 acc[8][4];
#pragma unroll
    for (int i = 0; i < 8; i++)
#pragma unroll
        for (int j = 0; j < 4; j++) acc[i][j] = (f32x4){0.f, 0.f, 0.f, 0.f};

    const int NT = K >> 6;   // BK=64

    auto stage = [&](int bi, int kt) {
#pragma unroll
        for (int p = 0; p < 4; p++) {
            const int dst = p * 4096 + wid * 512;   // wave-uniform (ushorts)
            gload_lds16(Az + (size_t)(m0 + rs[p]) * K + kt + kcs[p] * 8, &lA[bi][dst]);
            gload_lds16(Bz + (size_t)(n0 + rs[p]) * K + kt + kcs[p] * 8, &lB[bi][dst]);
        }
    };

    // prologue: stage tile 0, make it visible to all waves
    stage(0, 0);
    asm volatile("s_waitcnt vmcnt(0)" ::: "memory");
    __builtin_amdgcn_s_barrier();
    __builtin_amdgcn_sched_barrier(0);

    for (int t = 0; t < NT; t++) {
        const int bi = t & 1;
#pragma unroll
        for (int ph = 0; ph < 4; ph++) {
            const int ks32 = ph >> 1;      // K half of the tile
            const int mh   = ph & 1;       // M half of wave's rows
            const ushort* la = &lA[bi][(ks32 * 4 + hi) * 2048];
            const ushort* lb = &lB[bi][(ks32 * 4 + hi) * 2048];
            bf16x8 aF[4], bF[4];
#pragma unroll
            for (int i = 0; i < 4; i++)
                aF[i] = *(const bf16x8*)&la[(wr * 128 + (mh * 4 + i) * 16 + fr) * 8];
#pragma unroll
            for (int j = 0; j < 4; j++)
                bF[j] = *(const bf16x8*)&lb[(wc * 64 + j * 16 + fr) * 8];

            if (ph == 0 && t + 1 < NT) stage(bi ^ 1, (t + 1) << 6);

            __builtin_amdgcn_s_barrier();
            asm volatile("s_waitcnt lgkmcnt(0)" ::: "memory");
            __builtin_amdgcn_sched_barrier(0);

            __builtin_amdgcn_s_setprio(1);
#pragma unroll
            for (int i = 0; i < 4; i++)
#pragma unroll
                for (int j = 0; j < 4; j++)
                    acc[mh * 4 + i][j] = __builtin_amdgcn_mfma_f32_16x16x32_bf16(
                        aF[i], bF[j], acc[mh * 4 + i][j], 0, 0, 0);
            __builtin_amdgcn_s_setprio(0);

            if (ph == 3 && t + 1 < NT)
                asm volatile("s_waitcnt vmcnt(0)" ::: "memory");  // loads ~3 phases old
            __builtin_amdgcn_s_barrier();
            if (ph == 3) __builtin_amdgcn_sched_barrier(0);  // pin next-tile reads below
        }
    }

    // Epilogue. C/D layout (m89-verified): col = lane&15, row = (lane>>4)*4 + q
    const int cr = hi * 4;
    const int cc = fr;
#pragma unroll
    for (int m = 0; m < 8; m++) {
        const int row = m0 + wr * 128 + m * 16 + cr;
#pragma unroll
        for (int n = 0; n < 4; n++) {
            const int col = n0 + wc * 64 + n * 16 + cc;
            const float bv = bz[col];
#pragma unroll
            for (int q = 0; q < 4; q++) {
                float v = acc[m][n][q] + bv;
                if (MODE == 0) v = v > 0.f ? v : 0.f;
                Cz[(size_t)(row + q) * N + col] = (ushort)f2bf(v);
            }
        }
    }
}

// ---------------- small 128x128 GEMM (gate layer) ----------------
template<int MODE>
__global__ __launch_bounds__(256) void gemm_bt(
    const ushort* __restrict__ A,
    const ushort* __restrict__ Bw,
    const float* __restrict__ bias,
    ushort* __restrict__ Cb,
    int M, int N, int K)
{
    __shared__ ushort lA[128 * 64];
    __shared__ ushort lB[128 * 64];

    const int tid  = threadIdx.x;
    const int lane = tid & 63;
    const int wv   = tid >> 6;
    const int wr   = wv >> 1;
    const int wc   = wv & 1;
    const int m0   = blockIdx.x * 128;
    const int n0   = blockIdx.y * 128;

    const int srow = lane >> 3;
    const int scol = (lane & 7) * 8;
    const int fr   = lane & 15;
    const int fk   = (lane >> 4) * 8;

    f32x4 zero4 = {0.f, 0.f, 0.f, 0.f};
    f32x4 acc[4][4];
#pragma unroll
    for (int i = 0; i < 4; i++)
#pragma unroll
        for (int j = 0; j < 4; j++) acc[i][j] = zero4;

    for (int kt = 0; kt < K; kt += 64) {
        __syncthreads();
#pragma unroll
        for (int i = 0; i < 4; i++) {
            const int chunk = wv * 4 + i;
            const int row   = chunk * 8 + srow;
            gload_lds16(A  + (size_t)(m0 + row) * K + kt + scol, &lA[chunk * 512]);
            gload_lds16(Bw + (size_t)(n0 + row) * K + kt + scol, &lB[chunk * 512]);
        }
        __syncthreads();

#pragma unroll
        for (int ks = 0; ks < 2; ks++) {
            bf16x8 aF[4], bF[4];
#pragma unroll
            for (int i = 0; i < 4; i++)
                aF[i] = *(const bf16x8*)&lA[(wr * 64 + i * 16 + fr) * 64 + ks * 32 + fk];
#pragma unroll
            for (int j = 0; j < 4; j++)
                bF[j] = *(const bf16x8*)&lB[(wc * 64 + j * 16 + fr) * 64 + ks * 32 + fk];
#pragma unroll
            for (int i = 0; i < 4; i++)
#pragma unroll
                for (int j = 0; j < 4; j++)
                    acc[i][j] = __builtin_amdgcn_mfma_f32_16x16x32_bf16(
                        aF[i], bF[j], acc[i][j], 0, 0, 0);
        }
    }

    const int cr = (lane >> 4) * 4;
    const int cc = lane & 15;
#pragma unroll
    for (int i = 0; i < 4; i++) {
#pragma unroll
        for (int j = 0; j < 4; j++) {
            const int col = n0 + wc * 64 + j * 16 + cc;
            const float bv = bias[col];
#pragma unroll
            for (int q = 0; q < 4; q++) {
                const int row = m0 + wr * 64 + i * 16 + cr + q;
                float v = acc[i][j][q] + bv;
                if (MODE == 0) v = v > 0.f ? v : 0.f;
                Cb[(size_t)row * N + col] = (ushort)f2bf(v);
            }
        }
    }
}

// ---------------- LayerNorm + relu + residual (in place on z) ----------------
__global__ __launch_bounds__(256) void ln_kernel(
    ushort* __restrict__ z, const ushort* __restrict__ h,
    const float* __restrict__ g, const float* __restrict__ b, int B, int H)
{
    const int r = blockIdx.x;
    const int e = blockIdx.y;
    const int t = threadIdx.x;
    const size_t base = ((size_t)e * B + r) * H + t * 4;
    const float* ge = g + (size_t)e * H;
    const float* be = b + (size_t)e * H;

    bf16x4 zv = *(const bf16x4*)&z[base];
    float zf[4];
#pragma unroll
    for (int j = 0; j < 4; j++) zf[j] = bf2f(zv[j]);

    float s  = zf[0] + zf[1] + zf[2] + zf[3];
    float s2 = zf[0]*zf[0] + zf[1]*zf[1] + zf[2]*zf[2] + zf[3]*zf[3];
#pragma unroll
    for (int off = 32; off; off >>= 1) {
        s  += __shfl_xor(s, off);
        s2 += __shfl_xor(s2, off);
    }
    __shared__ float red[8];
    const int wv = t >> 6, lane = t & 63;
    if (lane == 0) { red[wv] = s; red[4 + wv] = s2; }
    __syncthreads();
    s  = red[0] + red[1] + red[2] + red[3];
    s2 = red[4] + red[5] + red[6] + red[7];

    const float mu  = s / (float)H;
    const float var = s2 / (float)H - mu * mu;
    const float rs  = rsqrtf(var + 1e-5f);

    bf16x4 hv = *(const bf16x4*)&h[base];
    bf16x4 o;
#pragma unroll
    for (int j = 0; j < 4; j++) {
        float gn = (zf[j] - mu) * rs * ge[t * 4 + j] + be[t * 4 + j];
        gn = gn > 0.f ? gn : 0.f;
        o[j] = f2bf(gn + bf2f(hv[j]));
    }
    *(bf16x4*)&z[base] = o;
}

// ---------------- gate: logits = gh @ Wg2^T + bg2 ; softmax over 8 ----------
__global__ __launch_bounds__(256) void gate2_kernel(
    const ushort* __restrict__ gh,   // [B,256] bf16
    const float* __restrict__ Wg2,   // [8,256]
    const float* __restrict__ bg2,   // [8]
    float* __restrict__ gate)        // [B,8]
{
    const int wv = threadIdx.x >> 6, lane = threadIdx.x & 63;
    const int r = blockIdx.x * 4 + wv;

    bf16x4 v = *(const bf16x4*)&gh[(size_t)r * 256 + lane * 4];
    float gf[4];
#pragma unroll
    for (int j = 0; j < 4; j++) gf[j] = bf2f(v[j]);

    float lg[8];
#pragma unroll
    for (int e = 0; e < 8; e++) {
        const float* w = Wg2 + e * 256 + lane * 4;
        float p = gf[0]*w[0] + gf[1]*w[1] + gf[2]*w[2] + gf[3]*w[3];
#pragma unroll
        for (int off = 32; off; off >>= 1) p += __shfl_xor(p, off);
        lg[e] = p + bg2[e];
    }
    float mx = lg[0];
#pragma unroll
    for (int e = 1; e < 8; e++) mx = fmaxf(mx, lg[e]);
    float ex[8], ssum = 0.f;
#pragma unroll
    for (int e = 0; e < 8; e++) { ex[e] = expf(lg[e] - mx); ssum += ex[e]; }
    const float inv = 1.f / ssum;
    float myex = 0.f;
#pragma unroll
    for (int e = 0; e < 8; e++) myex = (lane == e) ? ex[e] : myex;
    if (lane < 8) gate[(size_t)r * 8 + lane] = myex * inv;
}

// ---------------- gated combine: out (+)= sum_el gate[b,e0+el] * eo[el,b,:] --
__global__ __launch_bounds__(256) void combine_kernel(
    const ushort* __restrict__ eo,   // [eg, B, D] bf16
    const float* __restrict__ gate,  // [B, 8]
    float* __restrict__ out,         // [B, D]
    int total4, int e0, int eg, int init)
{
    const size_t BD = (size_t)8192 * 1024;
    int idx = blockIdx.x * 256 + threadIdx.x;
    int stride = gridDim.x * 256;
    for (int t = idx; t < total4; t += stride) {
        int b = t >> 8;                 // D/4 = 256
        int d = (t & 255) << 2;
        float4 s = {0.f, 0.f, 0.f, 0.f};
        for (int el = 0; el < eg; el++) {
            const float g = gate[(size_t)b * 8 + e0 + el];
            bf16x4 v = *(const bf16x4*)&eo[(size_t)el * BD + (size_t)b * 1024 + d];
            s.x += g * bf2f(v.x);
            s.y += g * bf2f(v.y);
            s.z += g * bf2f(v.z);
            s.w += g * bf2f(v.w);
        }
        float4* o = (float4*)&out[(size_t)b * 1024 + d];
        if (init) *o = s;
        else {
            float4 p = *o;
            p.x += s.x; p.y += s.y; p.z += s.z; p.w += s.w;
            *o = p;
        }
    }
}

// ---------------- host ----------------
extern "C" void kernel_launch(void* const* d_in, const int* in_sizes, int n_in,
                              void* d_out, int out_size, void* d_ws, size_t ws_size,
                              hipStream_t stream)
{
    const float* x   = (const float*)d_in[0];
    const float* W0  = (const float*)d_in[1];
    const float* b0  = (const float*)d_in[2];
    const float* W1  = (const float*)d_in[3];
    const float* b1  = (const float*)d_in[4];
    const float* lng = (const float*)d_in[5];
    const float* lnb = (const float*)d_in[6];
    const float* W2  = (const float*)d_in[7];
    const float* b2  = (const float*)d_in[8];
    const float* Wg1 = (const float*)d_in[9];
    const float* bg1 = (const float*)d_in[10];
    const float* Wg2 = (const float*)d_in[11];
    const float* bg2 = (const float*)d_in[12];
    float* out = (float*)d_out;

    const int B = 8192, D = 1024, H = 1024, E = 8, G = 256;

    char* ws = (char*)d_ws;
    ushort* x_bf  = (ushort*)ws;  ws += (size_t)B * D * 2;
    ushort* w0_bf = (ushort*)ws;  ws += (size_t)E * H * D * 2;
    ushort* w1_bf = (ushort*)ws;  ws += (size_t)E * H * H * 2;
    ushort* w2_bf = (ushort*)ws;  ws += (size_t)E * D * H * 2;
    ushort* wg1bf = (ushort*)ws;  ws += (size_t)G * D * 2;
    ushort* gh_bf = (ushort*)ws;  ws += (size_t)B * G * 2;
    float*  gatep = (float*)ws;   ws += (size_t)B * E * 4;

    size_t used  = (size_t)(ws - (char*)d_ws);
    size_t avail = (ws_size > used) ? ws_size - used : 0;
    size_t per_eg = (size_t)B * H * 2 * 2;   // h-buf + z-buf per expert
    int EG = 1;
    for (int cand = 8; cand >= 1; cand >>= 1)
        if ((size_t)cand * per_eg <= avail) { EG = cand; break; }

    ushort* hbuf = (ushort*)ws;
    ushort* zbuf = (ushort*)(ws + (size_t)EG * B * H * 2);

    auto cvt = [&](const float* src, ushort* dst, size_t n) {
        int n4 = (int)(n / 4);
        int blocks = (n4 + 255) / 256;
        if (blocks > 2048) blocks = 2048;
        cvt_kernel<<<dim3(blocks), dim3(256), 0, stream>>>(src, dst, n4);
    };
    cvt(x,   x_bf,  (size_t)B * D);
    cvt(W0,  w0_bf, (size_t)E * H * D);
    cvt(W1,  w1_bf, (size_t)E * H * H);
    cvt(W2,  w2_bf, (size_t)E * D * H);
    cvt(Wg1, wg1bf, (size_t)G * D);

    // gate
    gemm_bt<0><<<dim3(B / 128, G / 128), dim3(256), 0, stream>>>(
        x_bf, wg1bf, bg1, gh_bf, B, G, D);
    gate2_kernel<<<dim3(B / 4), dim3(256), 0, stream>>>(gh_bf, Wg2, bg2, gatep);

    const int cb4 = 2048;
    for (int e0 = 0; e0 < E; e0 += EG) {
        const int eg = (E - e0 < EG) ? (E - e0) : EG;
        // layer0: h = relu(x @ W0[e]^T + b0[e])
        gemm256<0><<<dim3(B / 256, H / 256, eg), dim3(512), 0, stream>>>(
            x_bf, w0_bf + (size_t)e0 * H * D, b0 + (size_t)e0 * H, hbuf,
            B, H, D, 0, (long)H * D, H, (long)B * H);
        // layer1: z = h @ W1[e]^T + b1[e]
        gemm256<1><<<dim3(B / 256, H / 256, eg), dim3(512), 0, stream>>>(
            hbuf, w1_bf + (size_t)e0 * H * H, b1 + (size_t)e0 * H, zbuf,
            B, H, H, (long)B * H, (long)H * H, H, (long)B * H);
        // LN -> relu -> +h
        ln_kernel<<<dim3(B, eg), dim3(256), 0, stream>>>(
            zbuf, hbuf, lng + (size_t)e0 * H, lnb + (size_t)e0 * H, B, H);
        // layer2: eo = hp @ W2[e]^T + b2[e]  (into hbuf)
        gemm256<1><<<dim3(B / 256, D / 256, eg), dim3(512), 0, stream>>>(
            zbuf, w2_bf + (size_t)e0 * D * H, b2 + (size_t)e0 * D, hbuf,
            B, D, H, (long)B * H, (long)D * H, D, (long)B * D);
        // gated combine
        combine_kernel<<<dim3(cb4), dim3(256), 0, stream>>>(
            hbuf, gatep, out, B * (D / 4), e0, eg, (e0 == 0) ? 1 : 0);
    }
}

// Round 5
// 713.719 us; speedup vs baseline: 1.6248x; 1.6248x over previous
//
#include <hip/hip_runtime.h>
#include <stdint.h>

typedef __attribute__((ext_vector_type(8))) short bf16x8;
typedef __attribute__((ext_vector_type(4))) short bf16x4;
typedef __attribute__((ext_vector_type(4))) float f32x4;

#define DEV static __device__ __forceinline__

DEV float bf2f(short u) {
    union { float f; uint32_t i; } v;
    v.i = ((uint32_t)(uint16_t)u) << 16;
    return v.f;
}
DEV short f2bf(float f) {
    union { float f; uint32_t i; } v; v.f = f;
    uint32_t r = v.i + 0x7fff + ((v.i >> 16) & 1);
    return (short)(r >> 16);
}

DEV void gload_lds16(const void* g, void* l) {
    __builtin_amdgcn_global_load_lds(
        (__attribute__((address_space(1))) void*)(void*)g,
        (__attribute__((address_space(3))) void*)l,
        16, 0, 0);
}

// ---------------- f32 -> bf16 conversion ----------------
__global__ __launch_bounds__(256) void cvt_kernel(const float* __restrict__ in,
                                                  ushort* __restrict__ out, int n4) {
    int idx = blockIdx.x * 256 + threadIdx.x;
    int stride = gridDim.x * 256;
    for (int i = idx; i < n4; i += stride) {
        float4 v = ((const float4*)in)[i];
        bf16x4 o;
        o.x = f2bf(v.x); o.y = f2bf(v.y); o.z = f2bf(v.z); o.w = f2bf(v.w);
        ((bf16x4*)out)[i] = o;
    }
}

// ============ 256x256 GEMM, BK=32, 4-deep ring, 2 phases/K-tile ============
// C[m,n] = epi(sum_k A[m,k]*Bw[n,k] + bias[n]), batched over blockIdx.z.
// LDS: 4 ring bufs x (16KB A + 16KB B), K-major [kchunk(4)][row(256)][8] ->
// conflict-free ds_read_b128 (R3/R4-verified 0 conflicts).
// Per phase: {4-8 ds_read_b128 ; 2 global_load_lds (tile t+3) ; barrier ;
// lgkmcnt(0) ; setprio(1) ; 16 MFMA ; setprio(0) ; barrier}.
// Counted gate once per K-tile: vmcnt(8) steady (tiles t+2,t+3 in flight),
// 4 / 0 only in the tail. Ring distance 3 makes staging race-free:
// buf[(t+3)&3]'s last readers finished at tile t-1's trailing barrier.
// MODE 0: relu(acc+bias) -> bf16 ;  MODE 1: acc+bias -> bf16
template<int MODE>
__global__ __launch_bounds__(512) void gemm256(
    const ushort* __restrict__ A,
    const ushort* __restrict__ Bw,
    const float* __restrict__ bias,
    ushort* __restrict__ Cb,
    int M, int N, int K,
    long sA, long sB, long sBias, long sC)
{
    __shared__ ushort lA[4][8192];   // 4 x 16 KB
    __shared__ ushort lB[4][8192];

    const int z = blockIdx.z;
    const ushort* Az = A + (size_t)z * sA;
    const ushort* Bz = Bw + (size_t)z * sB;
    const float*  bz = bias + (size_t)z * sBias;
    ushort*       Cz = Cb + (size_t)z * sC;

    const int tid  = threadIdx.x;
    const int lane = tid & 63;
    const int wid  = tid >> 6;        // 0..7
    const int wr   = wid >> 2;        // 0..1  (128 rows)
    const int wc   = wid & 3;         // 0..3  (64 cols)
    const int fr   = lane & 15;
    const int hi   = lane >> 4;       // 0..3 = kchunk
    const int m0   = blockIdx.x * 256;
    const int n0   = blockIdx.y * 256;

    // staging: unit u = p*512 + tid (16B units); row = u&255, kchunk = u>>8
    long offA[2], offB[2];
    int  udst[2];
#pragma unroll
    for (int p = 0; p < 2; p++) {
        const int u = p * 512 + tid;
        offA[p] = (long)(m0 + (u & 255)) * K + (u >> 8) * 8;
        offB[p] = (long)(n0 + (u & 255)) * K + (u >> 8) * 8;
        udst[p] = (p * 512 + wid * 64) * 8;   // wave-uniform ushort index
    }

    auto stageA = [&](int bi, int kt) {
#pragma unroll
        for (int p = 0; p < 2; p++)
            gload_lds16(Az + offA[p] + kt, &lA[bi][udst[p]]);
    };
    auto stageB = [&](int bi, int kt) {
#pragma unroll
        for (int p = 0; p < 2; p++)
            gload_lds16(Bz + offB[p] + kt, &lB[bi][udst[p]]);
    };

    f32x4 acc[8][4];
#pragma unroll
    for (int i = 0; i < 8; i++)
#pragma unroll
        for (int j = 0; j < 4; j++) acc[i][j] = (f32x4){0.f, 0.f, 0.f, 0.f};

    const int NT = K >> 5;   // BK=32 tiles

    // prologue: tiles 0,1,2 staged; gate tile 0 (outstanding = tiles 1,2 = 8)
    stageA(0, 0);  stageB(0, 0);
    stageA(1, 32); stageB(1, 32);
    stageA(2, 64); stageB(2, 64);
    asm volatile("s_waitcnt vmcnt(8)" ::: "memory");
    __builtin_amdgcn_s_barrier();

    const int rbase = hi * 256 + wr * 128;
    const int cbase = hi * 256 + wc * 64;

    for (int t = 0; t < NT; t++) {
        const int bi = t & 3;
        const ushort* la = lA[bi];
        const ushort* lb = lB[bi];
        bf16x8 aF[4], bF[4];

        // ---------- phase 0 (m-half 0) ----------
#pragma unroll
        for (int i = 0; i < 4; i++)
            aF[i] = *(const bf16x8*)&la[(rbase + i * 16 + fr) * 8];
#pragma unroll
        for (int j = 0; j < 4; j++)
            bF[j] = *(const bf16x8*)&lb[(cbase + j * 16 + fr) * 8];
        if (t + 3 < NT) stageA((t + 3) & 3, (t + 3) << 5);

        __builtin_amdgcn_s_barrier();
        asm volatile("s_waitcnt lgkmcnt(0)" ::: "memory");
        __builtin_amdgcn_sched_barrier(0);
        __builtin_amdgcn_s_setprio(1);
#pragma unroll
        for (int i = 0; i < 4; i++)
#pragma unroll
            for (int j = 0; j < 4; j++)
                acc[i][j] = __builtin_amdgcn_mfma_f32_16x16x32_bf16(
                    aF[i], bF[j], acc[i][j], 0, 0, 0);
        __builtin_amdgcn_s_setprio(0);
        __builtin_amdgcn_s_barrier();

        // ---------- phase 1 (m-half 1; bF reused from registers) ----------
#pragma unroll
        for (int i = 0; i < 4; i++)
            aF[i] = *(const bf16x8*)&la[(rbase + 64 + i * 16 + fr) * 8];
        if (t + 3 < NT) stageB((t + 3) & 3, (t + 3) << 5);

        // counted gate for tile t+1: outstanding = tiles t+2, t+3 (if staged)
        {
            const int last = (t + 3 < NT) ? (t + 3) : (NT - 1);
            const int ahead = last - (t + 1);
            if (ahead >= 2)      asm volatile("s_waitcnt vmcnt(8)" ::: "memory");
            else if (ahead == 1) asm volatile("s_waitcnt vmcnt(4)" ::: "memory");
            else                 asm volatile("s_waitcnt vmcnt(0)" ::: "memory");
        }
        __builtin_amdgcn_s_barrier();
        asm volatile("s_waitcnt lgkmcnt(0)" ::: "memory");
        __builtin_amdgcn_sched_barrier(0);
        __builtin_amdgcn_s_setprio(1);
#pragma unroll
        for (int i = 0; i < 4; i++)
#pragma unroll
            for (int j = 0; j < 4; j++)
                acc[4 + i][j] = __builtin_amdgcn_mfma_f32_16x16x32_bf16(
                    aF[i], bF[j], acc[4 + i][j], 0, 0, 0);
        __builtin_amdgcn_s_setprio(0);
        __builtin_amdgcn_s_barrier();
    }

    // Epilogue. C/D layout (m89-verified): col = lane&15, row = (lane>>4)*4 + q
    const int cr = hi * 4;
    const int cc = fr;
#pragma unroll
    for (int m = 0; m < 8; m++) {
        const int row = m0 + wr * 128 + m * 16 + cr;
#pragma unroll
        for (int n = 0; n < 4; n++) {
            const int col = n0 + wc * 64 + n * 16 + cc;
            const float bv = bz[col];
#pragma unroll
            for (int q = 0; q < 4; q++) {
                float v = acc[m][n][q] + bv;
                if (MODE == 0) v = v > 0.f ? v : 0.f;
                Cz[(size_t)(row + q) * N + col] = (ushort)f2bf(v);
            }
        }
    }
}

// ---------------- small 128x128 GEMM (gate layer) ----------------
template<int MODE>
__global__ __launch_bounds__(256) void gemm_bt(
    const ushort* __restrict__ A,
    const ushort* __restrict__ Bw,
    const float* __restrict__ bias,
    ushort* __restrict__ Cb,
    int M, int N, int K)
{
    __shared__ ushort lA[128 * 64];
    __shared__ ushort lB[128 * 64];

    const int tid  = threadIdx.x;
    const int lane = tid & 63;
    const int wv   = tid >> 6;
    const int wr   = wv >> 1;
    const int wc   = wv & 1;
    const int m0   = blockIdx.x * 128;
    const int n0   = blockIdx.y * 128;

    const int srow = lane >> 3;
    const int scol = (lane & 7) * 8;
    const int fr   = lane & 15;
    const int fk   = (lane >> 4) * 8;

    f32x4 zero4 = {0.f, 0.f, 0.f, 0.f};
    f32x4 acc[4][4];
#pragma unroll
    for (int i = 0; i < 4; i++)
#pragma unroll
        for (int j = 0; j < 4; j++) acc[i][j] = zero4;

    for (int kt = 0; kt < K; kt += 64) {
        __syncthreads();
#pragma unroll
        for (int i = 0; i < 4; i++) {
            const int chunk = wv * 4 + i;
            const int row   = chunk * 8 + srow;
            gload_lds16(A  + (size_t)(m0 + row) * K + kt + scol, &lA[chunk * 512]);
            gload_lds16(Bw + (size_t)(n0 + row) * K + kt + scol, &lB[chunk * 512]);
        }
        __syncthreads();

#pragma unroll
        for (int ks = 0; ks < 2; ks++) {
            bf16x8 aF[4], bF[4];
#pragma unroll
            for (int i = 0; i < 4; i++)
                aF[i] = *(const bf16x8*)&lA[(wr * 64 + i * 16 + fr) * 64 + ks * 32 + fk];
#pragma unroll
            for (int j = 0; j < 4; j++)
                bF[j] = *(const bf16x8*)&lB[(wc * 64 + j * 16 + fr) * 64 + ks * 32 + fk];
#pragma unroll
            for (int i = 0; i < 4; i++)
#pragma unroll
                for (int j = 0; j < 4; j++)
                    acc[i][j] = __builtin_amdgcn_mfma_f32_16x16x32_bf16(
                        aF[i], bF[j], acc[i][j], 0, 0, 0);
        }
    }

    const int cr = (lane >> 4) * 4;
    const int cc = lane & 15;
#pragma unroll
    for (int i = 0; i < 4; i++) {
#pragma unroll
        for (int j = 0; j < 4; j++) {
            const int col = n0 + wc * 64 + j * 16 + cc;
            const float bv = bias[col];
#pragma unroll
            for (int q = 0; q < 4; q++) {
                const int row = m0 + wr * 64 + i * 16 + cr + q;
                float v = acc[i][j][q] + bv;
                if (MODE == 0) v = v > 0.f ? v : 0.f;
                Cb[(size_t)row * N + col] = (ushort)f2bf(v);
            }
        }
    }
}

// ---------------- LayerNorm + relu + residual (in place on z) ----------------
__global__ __launch_bounds__(256) void ln_kernel(
    ushort* __restrict__ z, const ushort* __restrict__ h,
    const float* __restrict__ g, const float* __restrict__ b, int B, int H)
{
    const int r = blockIdx.x;
    const int e = blockIdx.y;
    const int t = threadIdx.x;
    const size_t base = ((size_t)e * B + r) * H + t * 4;
    const float* ge = g + (size_t)e * H;
    const float* be = b + (size_t)e * H;

    bf16x4 zv = *(const bf16x4*)&z[base];
    float zf[4];
#pragma unroll
    for (int j = 0; j < 4; j++) zf[j] = bf2f(zv[j]);

    float s  = zf[0] + zf[1] + zf[2] + zf[3];
    float s2 = zf[0]*zf[0] + zf[1]*zf[1] + zf[2]*zf[2] + zf[3]*zf[3];
#pragma unroll
    for (int off = 32; off; off >>= 1) {
        s  += __shfl_xor(s, off);
        s2 += __shfl_xor(s2, off);
    }
    __shared__ float red[8];
    const int wv = t >> 6, lane = t & 63;
    if (lane == 0) { red[wv] = s; red[4 + wv] = s2; }
    __syncthreads();
    s  = red[0] + red[1] + red[2] + red[3];
    s2 = red[4] + red[5] + red[6] + red[7];

    const float mu  = s / (float)H;
    const float var = s2 / (float)H - mu * mu;
    const float rs  = rsqrtf(var + 1e-5f);

    bf16x4 hv = *(const bf16x4*)&h[base];
    bf16x4 o;
#pragma unroll
    for (int j = 0; j < 4; j++) {
        float gn = (zf[j] - mu) * rs * ge[t * 4 + j] + be[t * 4 + j];
        gn = gn > 0.f ? gn : 0.f;
        o[j] = f2bf(gn + bf2f(hv[j]));
    }
    *(bf16x4*)&z[base] = o;
}

// ---------------- gate: logits = gh @ Wg2^T + bg2 ; softmax over 8 ----------
__global__ __launch_bounds__(256) void gate2_kernel(
    const ushort* __restrict__ gh,   // [B,256] bf16
    const float* __restrict__ Wg2,   // [8,256]
    const float* __restrict__ bg2,   // [8]
    float* __restrict__ gate)        // [B,8]
{
    const int wv = threadIdx.x >> 6, lane = threadIdx.x & 63;
    const int r = blockIdx.x * 4 + wv;

    bf16x4 v = *(const bf16x4*)&gh[(size_t)r * 256 + lane * 4];
    float gf[4];
#pragma unroll
    for (int j = 0; j < 4; j++) gf[j] = bf2f(v[j]);

    float lg[8];
#pragma unroll
    for (int e = 0; e < 8; e++) {
        const float* w = Wg2 + e * 256 + lane * 4;
        float p = gf[0]*w[0] + gf[1]*w[1] + gf[2]*w[2] + gf[3]*w[3];
#pragma unroll
        for (int off = 32; off; off >>= 1) p += __shfl_xor(p, off);
        lg[e] = p + bg2[e];
    }
    float mx = lg[0];
#pragma unroll
    for (int e = 1; e < 8; e++) mx = fmaxf(mx, lg[e]);
    float ex[8], ssum = 0.f;
#pragma unroll
    for (int e = 0; e < 8; e++) { ex[e] = expf(lg[e] - mx); ssum += ex[e]; }
    const float inv = 1.f / ssum;
    float myex = 0.f;
#pragma unroll
    for (int e = 0; e < 8; e++) myex = (lane == e) ? ex[e] : myex;
    if (lane < 8) gate[(size_t)r * 8 + lane] = myex * inv;
}

// ---------------- gated combine: out (+)= sum_el gate[b,e0+el] * eo[el,b,:] --
__global__ __launch_bounds__(256) void combine_kernel(
    const ushort* __restrict__ eo,   // [eg, B, D] bf16
    const float* __restrict__ gate,  // [B, 8]
    float* __restrict__ out,         // [B, D]
    int total4, int e0, int eg, int init)
{
    const size_t BD = (size_t)8192 * 1024;
    int idx = blockIdx.x * 256 + threadIdx.x;
    int stride = gridDim.x * 256;
    for (int t = idx; t < total4; t += stride) {
        int b = t >> 8;                 // D/4 = 256
        int d = (t & 255) << 2;
        float4 s = {0.f, 0.f, 0.f, 0.f};
        for (int el = 0; el < eg; el++) {
            const float g = gate[(size_t)b * 8 + e0 + el];
            bf16x4 v = *(const bf16x4*)&eo[(size_t)el * BD + (size_t)b * 1024 + d];
            s.x += g * bf2f(v.x);
            s.y += g * bf2f(v.y);
            s.z += g * bf2f(v.z);
            s.w += g * bf2f(v.w);
        }
        float4* o = (float4*)&out[(size_t)b * 1024 + d];
        if (init) *o = s;
        else {
            float4 p = *o;
            p.x += s.x; p.y += s.y; p.z += s.z; p.w += s.w;
            *o = p;
        }
    }
}

// ---------------- host ----------------
extern "C" void kernel_launch(void* const* d_in, const int* in_sizes, int n_in,
                              void* d_out, int out_size, void* d_ws, size_t ws_size,
                              hipStream_t stream)
{
    const float* x   = (const float*)d_in[0];
    const float* W0  = (const float*)d_in[1];
    const float* b0  = (const float*)d_in[2];
    const float* W1  = (const float*)d_in[3];
    const float* b1  = (const float*)d_in[4];
    const float* lng = (const float*)d_in[5];
    const float* lnb = (const float*)d_in[6];
    const float* W2  = (const float*)d_in[7];
    const float* b2  = (const float*)d_in[8];
    const float* Wg1 = (const float*)d_in[9];
    const float* bg1 = (const float*)d_in[10];
    const float* Wg2 = (const float*)d_in[11];
    const float* bg2 = (const float*)d_in[12];
    float* out = (float*)d_out;

    const int B = 8192, D = 1024, H = 1024, E = 8, G = 256;

    char* ws = (char*)d_ws;
    ushort* x_bf  = (ushort*)ws;  ws += (size_t)B * D * 2;
    ushort* w0_bf = (ushort*)ws;  ws += (size_t)E * H * D * 2;
    ushort* w1_bf = (ushort*)ws;  ws += (size_t)E * H * H * 2;
    ushort* w2_bf = (ushort*)ws;  ws += (size_t)E * D * H * 2;
    ushort* wg1bf = (ushort*)ws;  ws += (size_t)G * D * 2;
    ushort* gh_bf = (ushort*)ws;  ws += (size_t)B * G * 2;
    float*  gatep = (float*)ws;   ws += (size_t)B * E * 4;

    size_t used  = (size_t)(ws - (char*)d_ws);
    size_t avail = (ws_size > used) ? ws_size - used : 0;
    size_t per_eg = (size_t)B * H * 2 * 2;   // h-buf + z-buf per expert
    int EG = 1;
    for (int cand = 8; cand >= 1; cand >>= 1)
        if ((size_t)cand * per_eg <= avail) { EG = cand; break; }

    ushort* hbuf = (ushort*)ws;
    ushort* zbuf = (ushort*)(ws + (size_t)EG * B * H * 2);

    auto cvt = [&](const float* src, ushort* dst, size_t n) {
        int n4 = (int)(n / 4);
        int blocks = (n4 + 255) / 256;
        if (blocks > 2048) blocks = 2048;
        cvt_kernel<<<dim3(blocks), dim3(256), 0, stream>>>(src, dst, n4);
    };
    cvt(x,   x_bf,  (size_t)B * D);
    cvt(W0,  w0_bf, (size_t)E * H * D);
    cvt(W1,  w1_bf, (size_t)E * H * H);
    cvt(W2,  w2_bf, (size_t)E * D * H);
    cvt(Wg1, wg1bf, (size_t)G * D);

    // gate
    gemm_bt<0><<<dim3(B / 128, G / 128), dim3(256), 0, stream>>>(
        x_bf, wg1bf, bg1, gh_bf, B, G, D);
    gate2_kernel<<<dim3(B / 4), dim3(256), 0, stream>>>(gh_bf, Wg2, bg2, gatep);

    const int cb4 = 2048;
    for (int e0 = 0; e0 < E; e0 += EG) {
        const int eg = (E - e0 < EG) ? (E - e0) : EG;
        // layer0: h = relu(x @ W0[e]^T + b0[e])
        gemm256<0><<<dim3(B / 256, H / 256, eg), dim3(512), 0, stream>>>(
            x_bf, w0_bf + (size_t)e0 * H * D, b0 + (size_t)e0 * H, hbuf,
            B, H, D, 0, (long)H * D, H, (long)B * H);
        // layer1: z = h @ W1[e]^T + b1[e]
        gemm256<1><<<dim3(B / 256, H / 256, eg), dim3(512), 0, stream>>>(
            hbuf, w1_bf + (size_t)e0 * H * H, b1 + (size_t)e0 * H, zbuf,
            B, H, H, (long)B * H, (long)H * H, H, (long)B * H);
        // LN -> relu -> +h
        ln_kernel<<<dim3(B, eg), dim3(256), 0, stream>>>(
            zbuf, hbuf, lng + (size_t)e0 * H, lnb + (size_t)e0 * H, B, H);
        // layer2: eo = hp @ W2[e]^T + b2[e]  (into hbuf)
        gemm256<1><<<dim3(B / 256, D / 256, eg), dim3(512), 0, stream>>>(
            zbuf, w2_bf + (size_t)e0 * D * H, b2 + (size_t)e0 * D, hbuf,
            B, D, H, (long)B * H, (long)D * H, D, (long)B * D);
        // gated combine
        combine_kernel<<<dim3(cb4), dim3(256), 0, stream>>>(
            hbuf, gatep, out, B * (D / 4), e0, eg, (e0 == 0) ? 1 : 0);
    }
}

// Round 6
// 693.571 us; speedup vs baseline: 1.6720x; 1.0290x over previous
//
#include <hip/hip_runtime.h>
#include <stdint.h>

typedef __attribute__((ext_vector_type(8))) short bf16x8;
typedef __attribute__((ext_vector_type(4))) short bf16x4;
typedef __attribute__((ext_vector_type(4))) float f32x4;

#define DEV static __device__ __forceinline__

DEV float bf2f(short u) {
    union { float f; uint32_t i; } v;
    v.i = ((uint32_t)(uint16_t)u) << 16;
    return v.f;
}
DEV short f2bf(float f) {
    union { float f; uint32_t i; } v; v.f = f;
    uint32_t r = v.i + 0x7fff + ((v.i >> 16) & 1);
    return (short)(r >> 16);
}

DEV void gload_lds16(const void* g, void* l) {
    __builtin_amdgcn_global_load_lds(
        (__attribute__((address_space(1))) void*)(void*)g,
        (__attribute__((address_space(3))) void*)l,
        16, 0, 0);
}

// ---------------- f32 -> bf16 conversion ----------------
__global__ __launch_bounds__(256) void cvt_kernel(const float* __restrict__ in,
                                                  ushort* __restrict__ out, int n4) {
    int idx = blockIdx.x * 256 + threadIdx.x;
    int stride = gridDim.x * 256;
    for (int i = idx; i < n4; i += stride) {
        float4 v = ((const float4*)in)[i];
        bf16x4 o;
        o.x = f2bf(v.x); o.y = f2bf(v.y); o.z = f2bf(v.z); o.w = f2bf(v.w);
        ((bf16x4*)out)[i] = o;
    }
}

// ======== 256x256 GEMM, BK=64, dbuf, 4 phases/K-tile (m201 cadence) ========
// C[m,n] = epi(sum_k A[m,k]*Bw[n,k] + bias[n]), batched over blockIdx.z.
// LDS per buf: K-major [kchunk(8)][row(256)][8 ushorts] = 32KB (A and B),
// 2 bufs = 128 KiB; conflict-free (R3-R5 measured 0 conflicts).
// Phase p of tile t: {ds_read subtile ; stage 1 half-tile of t+1 ; barrier ;
// lgkmcnt(0) ; sched_barrier ; setprio(1) ; 16 MFMA ; setprio(0) ; [gate] ;
// barrier}.  Gates: vmcnt(4) at end of p1 (t's kh1 landed) and p3 (t+1's kh0
// landed); vmcnt(0) only at last tile's p1.  8 loads max in flight.
// MODE 0: relu(acc+bias) -> bf16 ;  MODE 1: acc+bias -> bf16
template<int MODE>
__global__ __launch_bounds__(512) void gemm256(
    const ushort* __restrict__ A,
    const ushort* __restrict__ Bw,
    const float* __restrict__ bias,
    ushort* __restrict__ Cb,
    int M, int N, int K,
    long sA, long sB, long sBias, long sC)
{
    __shared__ ushort lA[2][16384];   // 2 x 32 KB
    __shared__ ushort lB[2][16384];

    const int z = blockIdx.z;
    const ushort* Az = A + (size_t)z * sA;
    const ushort* Bz = Bw + (size_t)z * sB;
    const float*  bz = bias + (size_t)z * sBias;
    ushort*       Cz = Cb + (size_t)z * sC;

    const int tid  = threadIdx.x;
    const int lane = tid & 63;
    const int wid  = tid >> 6;        // 0..7
    const int wr   = wid >> 2;        // 0..1  (128 rows)
    const int wc   = wid & 3;         // 0..3  (64 cols)
    const int fr   = lane & 15;
    const int hi   = lane >> 4;       // 0..3
    const int m0   = blockIdx.x * 256;
    const int n0   = blockIdx.y * 256;

    // staging: i-th 16B-group (i = kh*2 + p), unit u = i*512 + tid
    // row = u&255, kchunk = u>>8 (0..7); dest linear in [kchunk][row] order.
    long offA[4], offB[4];
    int  dstU[4];
#pragma unroll
    for (int i = 0; i < 4; i++) {
        const int u = i * 512 + tid;
        const int row = u & 255, kc = u >> 8;
        offA[i] = (long)(m0 + row) * K + kc * 8;
        offB[i] = (long)(n0 + row) * K + kc * 8;
        dstU[i] = (i * 512 + wid * 64) * 8;   // wave-uniform ushort index
    }

    auto stA = [&](int bi, int kt, int kh) {
#pragma unroll
        for (int p = 0; p < 2; p++) {
            const int i = kh * 2 + p;
            gload_lds16(Az + offA[i] + kt, &lA[bi][dstU[i]]);
        }
    };
    auto stB = [&](int bi, int kt, int kh) {
#pragma unroll
        for (int p = 0; p < 2; p++) {
            const int i = kh * 2 + p;
            gload_lds16(Bz + offB[i] + kt, &lB[bi][dstU[i]]);
        }
    };

    f32x4 acc[8][4];
#pragma unroll
    for (int i = 0; i < 8; i++)
#pragma unroll
        for (int j = 0; j < 4; j++) acc[i][j] = (f32x4){0.f, 0.f, 0.f, 0.f};

    const int NT = K >> 6;   // BK=64

    // prologue: tile 0 fully staged; kh0 (first 4 loads) drained
    stA(0, 0, 0); stB(0, 0, 0); stA(0, 0, 1); stB(0, 0, 1);
    asm volatile("s_waitcnt vmcnt(4)" ::: "memory");
    __builtin_amdgcn_s_barrier();

    const int arow0 = wr * 128 + fr;
    const int brow0 = wc * 64 + fr;

    for (int t = 0; t < NT; t++) {
        const int bi = t & 1, nb = bi ^ 1;
        const int ktn = (t + 1) << 6;
        const ushort* la = lA[bi];
        const ushort* lb = lB[bi];
        bf16x8 aF[4], bF[4];

        // ---------- phase 0: kf=0, mh=0 ; stage A-kh0(t+1) ----------
#pragma unroll
        for (int i = 0; i < 4; i++)
            aF[i] = *(const bf16x8*)&la[(hi * 256 + arow0 + i * 16) * 8];
#pragma unroll
        for (int j = 0; j < 4; j++)
            bF[j] = *(const bf16x8*)&lb[(hi * 256 + brow0 + j * 16) * 8];
        if (t + 1 < NT) stA(nb, ktn, 0);
        __builtin_amdgcn_s_barrier();
        asm volatile("s_waitcnt lgkmcnt(0)" ::: "memory");
        __builtin_amdgcn_sched_barrier(0);
        __builtin_amdgcn_s_setprio(1);
#pragma unroll
        for (int i = 0; i < 4; i++)
#pragma unroll
            for (int j = 0; j < 4; j++)
                acc[i][j] = __builtin_amdgcn_mfma_f32_16x16x32_bf16(
                    aF[i], bF[j], acc[i][j], 0, 0, 0);
        __builtin_amdgcn_s_setprio(0);
        __builtin_amdgcn_s_barrier();

        // ---------- phase 1: kf=0, mh=1 (bF reused) ; stage B-kh0(t+1) ; mid-gate
#pragma unroll
        for (int i = 0; i < 4; i++)
            aF[i] = *(const bf16x8*)&la[(hi * 256 + arow0 + 64 + i * 16) * 8];
        if (t + 1 < NT) stB(nb, ktn, 0);
        __builtin_amdgcn_s_barrier();
        asm volatile("s_waitcnt lgkmcnt(0)" ::: "memory");
        __builtin_amdgcn_sched_barrier(0);
        __builtin_amdgcn_s_setprio(1);
#pragma unroll
        for (int i = 0; i < 4; i++)
#pragma unroll
            for (int j = 0; j < 4; j++)
                acc[4 + i][j] = __builtin_amdgcn_mfma_f32_16x16x32_bf16(
                    aF[i], bF[j], acc[4 + i][j], 0, 0, 0);
        __builtin_amdgcn_s_setprio(0);
        if (t == NT - 1) asm volatile("s_waitcnt vmcnt(0)" ::: "memory");
        else             asm volatile("s_waitcnt vmcnt(4)" ::: "memory");
        __builtin_amdgcn_s_barrier();

        // ---------- phase 2: kf=1, mh=0 ; stage A-kh1(t+1) ----------
#pragma unroll
        for (int i = 0; i < 4; i++)
            aF[i] = *(const bf16x8*)&la[((4 + hi) * 256 + arow0 + i * 16) * 8];
#pragma unroll
        for (int j = 0; j < 4; j++)
            bF[j] = *(const bf16x8*)&lb[((4 + hi) * 256 + brow0 + j * 16) * 8];
        if (t + 1 < NT) stA(nb, ktn, 1);
        __builtin_amdgcn_s_barrier();
        asm volatile("s_waitcnt lgkmcnt(0)" ::: "memory");
        __builtin_amdgcn_sched_barrier(0);
        __builtin_amdgcn_s_setprio(1);
#pragma unroll
        for (int i = 0; i < 4; i++)
#pragma unroll
            for (int j = 0; j < 4; j++)
                acc[i][j] = __builtin_amdgcn_mfma_f32_16x16x32_bf16(
                    aF[i], bF[j], acc[i][j], 0, 0, 0);
        __builtin_amdgcn_s_setprio(0);
        __builtin_amdgcn_s_barrier();

        // ---------- phase 3: kf=1, mh=1 (bF reused) ; stage B-kh1(t+1) ; end-gate
#pragma unroll
        for (int i = 0; i < 4; i++)
            aF[i] = *(const bf16x8*)&la[((4 + hi) * 256 + arow0 + 64 + i * 16) * 8];
        if (t + 1 < NT) stB(nb, ktn, 1);
        __builtin_amdgcn_s_barrier();
        asm volatile("s_waitcnt lgkmcnt(0)" ::: "memory");
        __builtin_amdgcn_sched_barrier(0);
        __builtin_amdgcn_s_setprio(1);
#pragma unroll
        for (int i = 0; i < 4; i++)
#pragma unroll
            for (int j = 0; j < 4; j++)
                acc[4 + i][j] = __builtin_amdgcn_mfma_f32_16x16x32_bf16(
                    aF[i], bF[j], acc[4 + i][j], 0, 0, 0);
        __builtin_amdgcn_s_setprio(0);
        if (t + 1 < NT) asm volatile("s_waitcnt vmcnt(4)" ::: "memory");
        __builtin_amdgcn_s_barrier();
    }

    // Epilogue. C/D layout (m89-verified): col = lane&15, row = (lane>>4)*4 + q
    const int cr = hi * 4;
    const int cc = fr;
#pragma unroll
    for (int m = 0; m < 8; m++) {
        const int row = m0 + wr * 128 + m * 16 + cr;
#pragma unroll
        for (int n = 0; n < 4; n++) {
            const int col = n0 + wc * 64 + n * 16 + cc;
            const float bv = bz[col];
#pragma unroll
            for (int q = 0; q < 4; q++) {
                float v = acc[m][n][q] + bv;
                if (MODE == 0) v = v > 0.f ? v : 0.f;
                Cz[(size_t)(row + q) * N + col] = (ushort)f2bf(v);
            }
        }
    }
}

// ---------------- small 128x128 GEMM (gate layer) ----------------
template<int MODE>
__global__ __launch_bounds__(256) void gemm_bt(
    const ushort* __restrict__ A,
    const ushort* __restrict__ Bw,
    const float* __restrict__ bias,
    ushort* __restrict__ Cb,
    int M, int N, int K)
{
    __shared__ ushort lA[128 * 64];
    __shared__ ushort lB[128 * 64];

    const int tid  = threadIdx.x;
    const int lane = tid & 63;
    const int wv   = tid >> 6;
    const int wr   = wv >> 1;
    const int wc   = wv & 1;
    const int m0   = blockIdx.x * 128;
    const int n0   = blockIdx.y * 128;

    const int srow = lane >> 3;
    const int scol = (lane & 7) * 8;
    const int fr   = lane & 15;
    const int fk   = (lane >> 4) * 8;

    f32x4 zero4 = {0.f, 0.f, 0.f, 0.f};
    f32x4 acc[4][4];
#pragma unroll
    for (int i = 0; i < 4; i++)
#pragma unroll
        for (int j = 0; j < 4; j++) acc[i][j] = zero4;

    for (int kt = 0; kt < K; kt += 64) {
        __syncthreads();
#pragma unroll
        for (int i = 0; i < 4; i++) {
            const int chunk = wv * 4 + i;
            const int row   = chunk * 8 + srow;
            gload_lds16(A  + (size_t)(m0 + row) * K + kt + scol, &lA[chunk * 512]);
            gload_lds16(Bw + (size_t)(n0 + row) * K + kt + scol, &lB[chunk * 512]);
        }
        __syncthreads();

#pragma unroll
        for (int ks = 0; ks < 2; ks++) {
            bf16x8 aF[4], bF[4];
#pragma unroll
            for (int i = 0; i < 4; i++)
                aF[i] = *(const bf16x8*)&lA[(wr * 64 + i * 16 + fr) * 64 + ks * 32 + fk];
#pragma unroll
            for (int j = 0; j < 4; j++)
                bF[j] = *(const bf16x8*)&lB[(wc * 64 + j * 16 + fr) * 64 + ks * 32 + fk];
#pragma unroll
            for (int i = 0; i < 4; i++)
#pragma unroll
                for (int j = 0; j < 4; j++)
                    acc[i][j] = __builtin_amdgcn_mfma_f32_16x16x32_bf16(
                        aF[i], bF[j], acc[i][j], 0, 0, 0);
        }
    }

    const int cr = (lane >> 4) * 4;
    const int cc = lane & 15;
#pragma unroll
    for (int i = 0; i < 4; i++) {
#pragma unroll
        for (int j = 0; j < 4; j++) {
            const int col = n0 + wc * 64 + j * 16 + cc;
            const float bv = bias[col];
#pragma unroll
            for (int q = 0; q < 4; q++) {
                const int row = m0 + wr * 64 + i * 16 + cr + q;
                float v = acc[i][j][q] + bv;
                if (MODE == 0) v = v > 0.f ? v : 0.f;
                Cb[(size_t)row * N + col] = (ushort)f2bf(v);
            }
        }
    }
}

// ---------------- LayerNorm + relu + residual (in place on z) ----------------
__global__ __launch_bounds__(256) void ln_kernel(
    ushort* __restrict__ z, const ushort* __restrict__ h,
    const float* __restrict__ g, const float* __restrict__ b, int B, int H)
{
    const int r = blockIdx.x;
    const int e = blockIdx.y;
    const int t = threadIdx.x;
    const size_t base = ((size_t)e * B + r) * H + t * 4;
    const float* ge = g + (size_t)e * H;
    const float* be = b + (size_t)e * H;

    bf16x4 zv = *(const bf16x4*)&z[base];
    float zf[4];
#pragma unroll
    for (int j = 0; j < 4; j++) zf[j] = bf2f(zv[j]);

    float s  = zf[0] + zf[1] + zf[2] + zf[3];
    float s2 = zf[0]*zf[0] + zf[1]*zf[1] + zf[2]*zf[2] + zf[3]*zf[3];
#pragma unroll
    for (int off = 32; off; off >>= 1) {
        s  += __shfl_xor(s, off);
        s2 += __shfl_xor(s2, off);
    }
    __shared__ float red[8];
    const int wv = t >> 6, lane = t & 63;
    if (lane == 0) { red[wv] = s; red[4 + wv] = s2; }
    __syncthreads();
    s  = red[0] + red[1] + red[2] + red[3];
    s2 = red[4] + red[5] + red[6] + red[7];

    const float mu  = s / (float)H;
    const float var = s2 / (float)H - mu * mu;
    const float rs  = rsqrtf(var + 1e-5f);

    bf16x4 hv = *(const bf16x4*)&h[base];
    bf16x4 o;
#pragma unroll
    for (int j = 0; j < 4; j++) {
        float gn = (zf[j] - mu) * rs * ge[t * 4 + j] + be[t * 4 + j];
        gn = gn > 0.f ? gn : 0.f;
        o[j] = f2bf(gn + bf2f(hv[j]));
    }
    *(bf16x4*)&z[base] = o;
}

// ---------------- gate: logits = gh @ Wg2^T + bg2 ; softmax over 8 ----------
__global__ __launch_bounds__(256) void gate2_kernel(
    const ushort* __restrict__ gh,   // [B,256] bf16
    const float* __restrict__ Wg2,   // [8,256]
    const float* __restrict__ bg2,   // [8]
    float* __restrict__ gate)        // [B,8]
{
    const int wv = threadIdx.x >> 6, lane = threadIdx.x & 63;
    const int r = blockIdx.x * 4 + wv;

    bf16x4 v = *(const bf16x4*)&gh[(size_t)r * 256 + lane * 4];
    float gf[4];
#pragma unroll
    for (int j = 0; j < 4; j++) gf[j] = bf2f(v[j]);

    float lg[8];
#pragma unroll
    for (int e = 0; e < 8; e++) {
        const float* w = Wg2 + e * 256 + lane * 4;
        float p = gf[0]*w[0] + gf[1]*w[1] + gf[2]*w[2] + gf[3]*w[3];
#pragma unroll
        for (int off = 32; off; off >>= 1) p += __shfl_xor(p, off);
        lg[e] = p + bg2[e];
    }
    float mx = lg[0];
#pragma unroll
    for (int e = 1; e < 8; e++) mx = fmaxf(mx, lg[e]);
    float ex[8], ssum = 0.f;
#pragma unroll
    for (int e = 0; e < 8; e++) { ex[e] = expf(lg[e] - mx); ssum += ex[e]; }
    const float inv = 1.f / ssum;
    float myex = 0.f;
#pragma unroll
    for (int e = 0; e < 8; e++) myex = (lane == e) ? ex[e] : myex;
    if (lane < 8) gate[(size_t)r * 8 + lane] = myex * inv;
}

// ---------------- gated combine: out (+)= sum_el gate[b,e0+el] * eo[el,b,:] --
__global__ __launch_bounds__(256) void combine_kernel(
    const ushort* __restrict__ eo,   // [eg, B, D] bf16
    const float* __restrict__ gate,  // [B, 8]
    float* __restrict__ out,         // [B, D]
    int total4, int e0, int eg, int init)
{
    const size_t BD = (size_t)8192 * 1024;
    int idx = blockIdx.x * 256 + threadIdx.x;
    int stride = gridDim.x * 256;
    for (int t = idx; t < total4; t += stride) {
        int b = t >> 8;                 // D/4 = 256
        int d = (t & 255) << 2;
        float4 s = {0.f, 0.f, 0.f, 0.f};
        for (int el = 0; el < eg; el++) {
            const float g = gate[(size_t)b * 8 + e0 + el];
            bf16x4 v = *(const bf16x4*)&eo[(size_t)el * BD + (size_t)b * 1024 + d];
            s.x += g * bf2f(v.x);
            s.y += g * bf2f(v.y);
            s.z += g * bf2f(v.z);
            s.w += g * bf2f(v.w);
        }
        float4* o = (float4*)&out[(size_t)b * 1024 + d];
        if (init) *o = s;
        else {
            float4 p = *o;
            p.x += s.x; p.y += s.y; p.z += s.z; p.w += s.w;
            *o = p;
        }
    }
}

// ---------------- host ----------------
extern "C" void kernel_launch(void* const* d_in, const int* in_sizes, int n_in,
                              void* d_out, int out_size, void* d_ws, size_t ws_size,
                              hipStream_t stream)
{
    const float* x   = (const float*)d_in[0];
    const float* W0  = (const float*)d_in[1];
    const float* b0  = (const float*)d_in[2];
    const float* W1  = (const float*)d_in[3];
    const float* b1  = (const float*)d_in[4];
    const float* lng = (const float*)d_in[5];
    const float* lnb = (const float*)d_in[6];
    const float* W2  = (const float*)d_in[7];
    const float* b2  = (const float*)d_in[8];
    const float* Wg1 = (const float*)d_in[9];
    const float* bg1 = (const float*)d_in[10];
    const float* Wg2 = (const float*)d_in[11];
    const float* bg2 = (const float*)d_in[12];
    float* out = (float*)d_out;

    const int B = 8192, D = 1024, H = 1024, E = 8, G = 256;

    char* ws = (char*)d_ws;
    ushort* x_bf  = (ushort*)ws;  ws += (size_t)B * D * 2;
    ushort* w0_bf = (ushort*)ws;  ws += (size_t)E * H * D * 2;
    ushort* w1_bf = (ushort*)ws;  ws += (size_t)E * H * H * 2;
    ushort* w2_bf = (ushort*)ws;  ws += (size_t)E * D * H * 2;
    ushort* wg1bf = (ushort*)ws;  ws += (size_t)G * D * 2;
    ushort* gh_bf = (ushort*)ws;  ws += (size_t)B * G * 2;
    float*  gatep = (float*)ws;   ws += (size_t)B * E * 4;

    size_t used  = (size_t)(ws - (char*)d_ws);
    size_t avail = (ws_size > used) ? ws_size - used : 0;
    size_t per_eg = (size_t)B * H * 2 * 2;   // h-buf + z-buf per expert
    int EG = 1;
    for (int cand = 8; cand >= 1; cand >>= 1)
        if ((size_t)cand * per_eg <= avail) { EG = cand; break; }

    ushort* hbuf = (ushort*)ws;
    ushort* zbuf = (ushort*)(ws + (size_t)EG * B * H * 2);

    auto cvt = [&](const float* src, ushort* dst, size_t n) {
        int n4 = (int)(n / 4);
        int blocks = (n4 + 255) / 256;
        if (blocks > 2048) blocks = 2048;
        cvt_kernel<<<dim3(blocks), dim3(256), 0, stream>>>(src, dst, n4);
    };
    cvt(x,   x_bf,  (size_t)B * D);
    cvt(W0,  w0_bf, (size_t)E * H * D);
    cvt(W1,  w1_bf, (size_t)E * H * H);
    cvt(W2,  w2_bf, (size_t)E * D * H);
    cvt(Wg1, wg1bf, (size_t)G * D);

    // gate
    gemm_bt<0><<<dim3(B / 128, G / 128), dim3(256), 0, stream>>>(
        x_bf, wg1bf, bg1, gh_bf, B, G, D);
    gate2_kernel<<<dim3(B / 4), dim3(256), 0, stream>>>(gh_bf, Wg2, bg2, gatep);

    const int cb4 = 2048;
    for (int e0 = 0; e0 < E; e0 += EG) {
        const int eg = (E - e0 < EG) ? (E - e0) : EG;
        // layer0: h = relu(x @ W0[e]^T + b0[e])
        gemm256<0><<<dim3(B / 256, H / 256, eg), dim3(512), 0, stream>>>(
            x_bf, w0_bf + (size_t)e0 * H * D, b0 + (size_t)e0 * H, hbuf,
            B, H, D, 0, (long)H * D, H, (long)B * H);
        // layer1: z = h @ W1[e]^T + b1[e]
        gemm256<1><<<dim3(B / 256, H / 256, eg), dim3(512), 0, stream>>>(
            hbuf, w1_bf + (size_t)e0 * H * H, b1 + (size_t)e0 * H, zbuf,
            B, H, H, (long)B * H, (long)H * H, H, (long)B * H);
        // LN -> relu -> +h
        ln_kernel<<<dim3(B, eg), dim3(256), 0, stream>>>(
            zbuf, hbuf, lng + (size_t)e0 * H, lnb + (size_t)e0 * H, B, H);
        // layer2: eo = hp @ W2[e]^T + b2[e]  (into hbuf)
        gemm256<1><<<dim3(B / 256, D / 256, eg), dim3(512), 0, stream>>>(
            zbuf, w2_bf + (size_t)e0 * D * H, b2 + (size_t)e0 * D, hbuf,
            B, D, H, (long)B * H, (long)D * H, D, (long)B * D);
        // gated combine
        combine_kernel<<<dim3(cb4), dim3(256), 0, stream>>>(
            hbuf, gatep, out, B * (D / 4), e0, eg, (e0 == 0) ? 1 : 0);
    }
}

// Round 7
// 608.978 us; speedup vs baseline: 1.9042x; 1.1389x over previous
//
#include <hip/hip_runtime.h>
#include <stdint.h>

typedef __attribute__((ext_vector_type(8))) short bf16x8;
typedef __attribute__((ext_vector_type(4))) short bf16x4;
typedef __attribute__((ext_vector_type(4))) float f32x4;

#define DEV static __device__ __forceinline__

DEV float bf2f(short u) {
    union { float f; uint32_t i; } v;
    v.i = ((uint32_t)(uint16_t)u) << 16;
    return v.f;
}
DEV short f2bf(float f) {
    union { float f; uint32_t i; } v; v.f = f;
    uint32_t r = v.i + 0x7fff + ((v.i >> 16) & 1);
    return (short)(r >> 16);
}

DEV void gload_lds16(const void* g, void* l) {
    __builtin_amdgcn_global_load_lds(
        (__attribute__((address_space(1))) void*)(void*)g,
        (__attribute__((address_space(3))) void*)l,
        16, 0, 0);
}

// ---------------- f32 -> bf16 conversion ----------------
__global__ __launch_bounds__(256) void cvt_kernel(const float* __restrict__ in,
                                                  ushort* __restrict__ out, int n4) {
    int idx = blockIdx.x * 256 + threadIdx.x;
    int stride = gridDim.x * 256;
    for (int i = idx; i < n4; i += stride) {
        float4 v = ((const float4*)in)[i];
        bf16x4 o;
        o.x = f2bf(v.x); o.y = f2bf(v.y); o.z = f2bf(v.z); o.w = f2bf(v.w);
        ((bf16x4*)out)[i] = o;
    }
}

// ======== 256x256 GEMM, BK=64, dbuf, 4 phases/K-tile, XOR-swizzled LDS ======
// LDS per buf: row-major [256 rows][64 k] bf16 (32 KB), 16B-unit XOR swizzle:
// physical unit u holds (row=u>>3, k8=(u&7)^(row&7)).
//  - staging: unit g=p*512+tid -> 8 consecutive lanes read ONE 128B row-line
//    (permuted within the line) => fully coalesced global; LDS dest linear.
//  - frag read: la[row*64 + ((kf*4+hi)^(fr&7))*8] => banks perfectly even
//    (8 words/bank/wave-read = minimum), conflict-free.
// Phases per K-tile t: ph0{read kf0/mh0 A+B; stage A(t+1)}, ph1{kf0/mh1 A;
// stage B(t+1)}, ph2{kf1/mh0 A+B}, ph3{kf1/mh1 A; gate vmcnt(0) on t+1's
// loads (issued 2-3 phases earlier => cheap drain)}. Each phase barrier-paired
// with lgkmcnt(0)+sched_barrier before its 16-MFMA setprio cluster.
// MODE 0: relu(acc+bias) -> bf16 ;  MODE 1: acc+bias -> bf16
template<int MODE>
__global__ __launch_bounds__(512) void gemm256(
    const ushort* __restrict__ A,
    const ushort* __restrict__ Bw,
    const float* __restrict__ bias,
    ushort* __restrict__ Cb,
    int M, int N, int K,
    long sA, long sB, long sBias, long sC)
{
    __shared__ ushort lA[2][16384];   // 2 x 32 KB
    __shared__ ushort lB[2][16384];

    const int z = blockIdx.z;
    const ushort* Az = A + (size_t)z * sA;
    const ushort* Bz = Bw + (size_t)z * sB;
    const float*  bz = bias + (size_t)z * sBias;
    ushort*       Cz = Cb + (size_t)z * sC;

    const int tid  = threadIdx.x;
    const int lane = tid & 63;
    const int wid  = tid >> 6;        // 0..7
    const int wr   = wid >> 2;        // 0..1  (128 rows)
    const int wc   = wid & 3;         // 0..3  (64 cols)
    const int fr   = lane & 15;
    const int hi   = lane >> 4;       // 0..3
    const int m0   = blockIdx.x * 256;
    const int n0   = blockIdx.y * 256;

    // lane-constant swizzled k-offsets (ushorts) for frag reads
    const int fr8 = fr & 7;
    const int sw0 = ((0 + hi) ^ fr8) * 8;   // kf=0
    const int sw1 = ((4 + hi) ^ fr8) * 8;   // kf=1

    // staging: pass p, global unit g = p*512 + tid; row = g>>3;
    // logical k-unit = (g&7) ^ (row&7)  (inverse == forward, involution)
    long offA[4], offB[4];
    int  dstU[4];
#pragma unroll
    for (int p = 0; p < 4; p++) {
        const int g   = p * 512 + tid;
        const int row = g >> 3;
        const int ku  = (g & 7) ^ (row & 7);
        offA[p] = (long)(m0 + row) * K + ku * 8;
        offB[p] = (long)(n0 + row) * K + ku * 8;
        dstU[p] = (p * 512 + wid * 64) * 8;   // wave-uniform ushort index
    }

    auto stA = [&](int bi, int kt) {
#pragma unroll
        for (int p = 0; p < 4; p++)
            gload_lds16(Az + offA[p] + kt, &lA[bi][dstU[p]]);
    };
    auto stB = [&](int bi, int kt) {
#pragma unroll
        for (int p = 0; p < 4; p++)
            gload_lds16(Bz + offB[p] + kt, &lB[bi][dstU[p]]);
    };

    f32x4 acc[8][4];
#pragma unroll
    for (int i = 0; i < 8; i++)
#pragma unroll
        for (int j = 0; j < 4; j++) acc[i][j] = (f32x4){0.f, 0.f, 0.f, 0.f};

    const int NT = K >> 6;   // BK=64

    // prologue: tile 0 fully staged and drained
    stA(0, 0); stB(0, 0);
    asm volatile("s_waitcnt vmcnt(0)" ::: "memory");
    __builtin_amdgcn_s_barrier();

    const int ar0 = wr * 128 + fr;     // A row base (mh=0)
    const int br0 = wc * 64 + fr;      // B row base

    for (int t = 0; t < NT; t++) {
        const int bi = t & 1, nb = bi ^ 1;
        const int ktn = (t + 1) << 6;
        const ushort* la = lA[bi];
        const ushort* lb = lB[bi];
        bf16x8 aF[4], bF[4];

        // ---------- phase 0: kf0, mh0 ; stage A(t+1) ----------
#pragma unroll
        for (int i = 0; i < 4; i++)
            aF[i] = *(const bf16x8*)&la[(ar0 + i * 16) * 64 + sw0];
#pragma unroll
        for (int j = 0; j < 4; j++)
            bF[j] = *(const bf16x8*)&lb[(br0 + j * 16) * 64 + sw0];
        if (t + 1 < NT) stA(nb, ktn);
        __builtin_amdgcn_s_barrier();
        asm volatile("s_waitcnt lgkmcnt(0)" ::: "memory");
        __builtin_amdgcn_sched_barrier(0);
        __builtin_amdgcn_s_setprio(1);
#pragma unroll
        for (int i = 0; i < 4; i++)
#pragma unroll
            for (int j = 0; j < 4; j++)
                acc[i][j] = __builtin_amdgcn_mfma_f32_16x16x32_bf16(
                    aF[i], bF[j], acc[i][j], 0, 0, 0);
        __builtin_amdgcn_s_setprio(0);
        __builtin_amdgcn_s_barrier();

        // ---------- phase 1: kf0, mh1 (bF reused) ; stage B(t+1) ----------
#pragma unroll
        for (int i = 0; i < 4; i++)
            aF[i] = *(const bf16x8*)&la[(ar0 + 64 + i * 16) * 64 + sw0];
        if (t + 1 < NT) stB(nb, ktn);
        __builtin_amdgcn_s_barrier();
        asm volatile("s_waitcnt lgkmcnt(0)" ::: "memory");
        __builtin_amdgcn_sched_barrier(0);
        __builtin_amdgcn_s_setprio(1);
#pragma unroll
        for (int i = 0; i < 4; i++)
#pragma unroll
            for (int j = 0; j < 4; j++)
                acc[4 + i][j] = __builtin_amdgcn_mfma_f32_16x16x32_bf16(
                    aF[i], bF[j], acc[4 + i][j], 0, 0, 0);
        __builtin_amdgcn_s_setprio(0);
        __builtin_amdgcn_s_barrier();

        // ---------- phase 2: kf1, mh0 ----------
#pragma unroll
        for (int i = 0; i < 4; i++)
            aF[i] = *(const bf16x8*)&la[(ar0 + i * 16) * 64 + sw1];
#pragma unroll
        for (int j = 0; j < 4; j++)
            bF[j] = *(const bf16x8*)&lb[(br0 + j * 16) * 64 + sw1];
        __builtin_amdgcn_s_barrier();
        asm volatile("s_waitcnt lgkmcnt(0)" ::: "memory");
        __builtin_amdgcn_sched_barrier(0);
        __builtin_amdgcn_s_setprio(1);
#pragma unroll
        for (int i = 0; i < 4; i++)
#pragma unroll
            for (int j = 0; j < 4; j++)
                acc[i][j] = __builtin_amdgcn_mfma_f32_16x16x32_bf16(
                    aF[i], bF[j], acc[i][j], 0, 0, 0);
        __builtin_amdgcn_s_setprio(0);
        __builtin_amdgcn_s_barrier();

        // ---------- phase 3: kf1, mh1 (bF reused) ; end-gate ----------
#pragma unroll
        for (int i = 0; i < 4; i++)
            aF[i] = *(const bf16x8*)&la[(ar0 + 64 + i * 16) * 64 + sw1];
        __builtin_amdgcn_s_barrier();
        asm volatile("s_waitcnt lgkmcnt(0)" ::: "memory");
        __builtin_amdgcn_sched_barrier(0);
        __builtin_amdgcn_s_setprio(1);
#pragma unroll
        for (int i = 0; i < 4; i++)
#pragma unroll
            for (int j = 0; j < 4; j++)
                acc[4 + i][j] = __builtin_amdgcn_mfma_f32_16x16x32_bf16(
                    aF[i], bF[j], acc[4 + i][j], 0, 0, 0);
        __builtin_amdgcn_s_setprio(0);
        // tile t+1's 8 loads were issued 2-3 phases ago -> near-complete drain
        if (t + 1 < NT) asm volatile("s_waitcnt vmcnt(0)" ::: "memory");
        __builtin_amdgcn_s_barrier();
        __builtin_amdgcn_sched_barrier(0);
    }

    // Epilogue. C/D layout (m89-verified): col = lane&15, row = (lane>>4)*4 + q
    const int cr = hi * 4;
    const int cc = fr;
#pragma unroll
    for (int m = 0; m < 8; m++) {
        const int row = m0 + wr * 128 + m * 16 + cr;
#pragma unroll
        for (int n = 0; n < 4; n++) {
            const int col = n0 + wc * 64 + n * 16 + cc;
            const float bv = bz[col];
#pragma unroll
            for (int q = 0; q < 4; q++) {
                float v = acc[m][n][q] + bv;
                if (MODE == 0) v = v > 0.f ? v : 0.f;
                Cz[(size_t)(row + q) * N + col] = (ushort)f2bf(v);
            }
        }
    }
}

// ---------------- small 128x128 GEMM (gate layer) ----------------
template<int MODE>
__global__ __launch_bounds__(256) void gemm_bt(
    const ushort* __restrict__ A,
    const ushort* __restrict__ Bw,
    const float* __restrict__ bias,
    ushort* __restrict__ Cb,
    int M, int N, int K)
{
    __shared__ ushort lA[128 * 64];
    __shared__ ushort lB[128 * 64];

    const int tid  = threadIdx.x;
    const int lane = tid & 63;
    const int wv   = tid >> 6;
    const int wr   = wv >> 1;
    const int wc   = wv & 1;
    const int m0   = blockIdx.x * 128;
    const int n0   = blockIdx.y * 128;

    const int srow = lane >> 3;
    const int scol = (lane & 7) * 8;
    const int fr   = lane & 15;
    const int fk   = (lane >> 4) * 8;

    f32x4 zero4 = {0.f, 0.f, 0.f, 0.f};
    f32x4 acc[4][4];
#pragma unroll
    for (int i = 0; i < 4; i++)
#pragma unroll
        for (int j = 0; j < 4; j++) acc[i][j] = zero4;

    for (int kt = 0; kt < K; kt += 64) {
        __syncthreads();
#pragma unroll
        for (int i = 0; i < 4; i++) {
            const int chunk = wv * 4 + i;
            const int row   = chunk * 8 + srow;
            gload_lds16(A  + (size_t)(m0 + row) * K + kt + scol, &lA[chunk * 512]);
            gload_lds16(Bw + (size_t)(n0 + row) * K + kt + scol, &lB[chunk * 512]);
        }
        __syncthreads();

#pragma unroll
        for (int ks = 0; ks < 2; ks++) {
            bf16x8 aF[4], bF[4];
#pragma unroll
            for (int i = 0; i < 4; i++)
                aF[i] = *(const bf16x8*)&lA[(wr * 64 + i * 16 + fr) * 64 + ks * 32 + fk];
#pragma unroll
            for (int j = 0; j < 4; j++)
                bF[j] = *(const bf16x8*)&lB[(wc * 64 + j * 16 + fr) * 64 + ks * 32 + fk];
#pragma unroll
            for (int i = 0; i < 4; i++)
#pragma unroll
                for (int j = 0; j < 4; j++)
                    acc[i][j] = __builtin_amdgcn_mfma_f32_16x16x32_bf16(
                        aF[i], bF[j], acc[i][j], 0, 0, 0);
        }
    }

    const int cr = (lane >> 4) * 4;
    const int cc = lane & 15;
#pragma unroll
    for (int i = 0; i < 4; i++) {
#pragma unroll
        for (int j = 0; j < 4; j++) {
            const int col = n0 + wc * 64 + j * 16 + cc;
            const float bv = bias[col];
#pragma unroll
            for (int q = 0; q < 4; q++) {
                const int row = m0 + wr * 64 + i * 16 + cr + q;
                float v = acc[i][j][q] + bv;
                if (MODE == 0) v = v > 0.f ? v : 0.f;
                Cb[(size_t)row * N + col] = (ushort)f2bf(v);
            }
        }
    }
}

// ---------------- LayerNorm + relu + residual (in place on z) ----------------
__global__ __launch_bounds__(256) void ln_kernel(
    ushort* __restrict__ z, const ushort* __restrict__ h,
    const float* __restrict__ g, const float* __restrict__ b, int B, int H)
{
    const int r = blockIdx.x;
    const int e = blockIdx.y;
    const int t = threadIdx.x;
    const size_t base = ((size_t)e * B + r) * H + t * 4;
    const float* ge = g + (size_t)e * H;
    const float* be = b + (size_t)e * H;

    bf16x4 zv = *(const bf16x4*)&z[base];
    float zf[4];
#pragma unroll
    for (int j = 0; j < 4; j++) zf[j] = bf2f(zv[j]);

    float s  = zf[0] + zf[1] + zf[2] + zf[3];
    float s2 = zf[0]*zf[0] + zf[1]*zf[1] + zf[2]*zf[2] + zf[3]*zf[3];
#pragma unroll
    for (int off = 32; off; off >>= 1) {
        s  += __shfl_xor(s, off);
        s2 += __shfl_xor(s2, off);
    }
    __shared__ float red[8];
    const int wv = t >> 6, lane = t & 63;
    if (lane == 0) { red[wv] = s; red[4 + wv] = s2; }
    __syncthreads();
    s  = red[0] + red[1] + red[2] + red[3];
    s2 = red[4] + red[5] + red[6] + red[7];

    const float mu  = s / (float)H;
    const float var = s2 / (float)H - mu * mu;
    const float rs  = rsqrtf(var + 1e-5f);

    bf16x4 hv = *(const bf16x4*)&h[base];
    bf16x4 o;
#pragma unroll
    for (int j = 0; j < 4; j++) {
        float gn = (zf[j] - mu) * rs * ge[t * 4 + j] + be[t * 4 + j];
        gn = gn > 0.f ? gn : 0.f;
        o[j] = f2bf(gn + bf2f(hv[j]));
    }
    *(bf16x4*)&z[base] = o;
}

// ---------------- gate: logits = gh @ Wg2^T + bg2 ; softmax over 8 ----------
__global__ __launch_bounds__(256) void gate2_kernel(
    const ushort* __restrict__ gh,   // [B,256] bf16
    const float* __restrict__ Wg2,   // [8,256]
    const float* __restrict__ bg2,   // [8]
    float* __restrict__ gate)        // [B,8]
{
    const int wv = threadIdx.x >> 6, lane = threadIdx.x & 63;
    const int r = blockIdx.x * 4 + wv;

    bf16x4 v = *(const bf16x4*)&gh[(size_t)r * 256 + lane * 4];
    float gf[4];
#pragma unroll
    for (int j = 0; j < 4; j++) gf[j] = bf2f(v[j]);

    float lg[8];
#pragma unroll
    for (int e = 0; e < 8; e++) {
        const float* w = Wg2 + e * 256 + lane * 4;
        float p = gf[0]*w[0] + gf[1]*w[1] + gf[2]*w[2] + gf[3]*w[3];
#pragma unroll
        for (int off = 32; off; off >>= 1) p += __shfl_xor(p, off);
        lg[e] = p + bg2[e];
    }
    float mx = lg[0];
#pragma unroll
    for (int e = 1; e < 8; e++) mx = fmaxf(mx, lg[e]);
    float ex[8], ssum = 0.f;
#pragma unroll
    for (int e = 0; e < 8; e++) { ex[e] = expf(lg[e] - mx); ssum += ex[e]; }
    const float inv = 1.f / ssum;
    float myex = 0.f;
#pragma unroll
    for (int e = 0; e < 8; e++) myex = (lane == e) ? ex[e] : myex;
    if (lane < 8) gate[(size_t)r * 8 + lane] = myex * inv;
}

// ---------------- gated combine: out (+)= sum_el gate[b,e0+el] * eo[el,b,:] --
__global__ __launch_bounds__(256) void combine_kernel(
    const ushort* __restrict__ eo,   // [eg, B, D] bf16
    const float* __restrict__ gate,  // [B, 8]
    float* __restrict__ out,         // [B, D]
    int total4, int e0, int eg, int init)
{
    const size_t BD = (size_t)8192 * 1024;
    int idx = blockIdx.x * 256 + threadIdx.x;
    int stride = gridDim.x * 256;
    for (int t = idx; t < total4; t += stride) {
        int b = t >> 8;                 // D/4 = 256
        int d = (t & 255) << 2;
        float4 s = {0.f, 0.f, 0.f, 0.f};
        for (int el = 0; el < eg; el++) {
            const float g = gate[(size_t)b * 8 + e0 + el];
            bf16x4 v = *(const bf16x4*)&eo[(size_t)el * BD + (size_t)b * 1024 + d];
            s.x += g * bf2f(v.x);
            s.y += g * bf2f(v.y);
            s.z += g * bf2f(v.z);
            s.w += g * bf2f(v.w);
        }
        float4* o = (float4*)&out[(size_t)b * 1024 + d];
        if (init) *o = s;
        else {
            float4 p = *o;
            p.x += s.x; p.y += s.y; p.z += s.z; p.w += s.w;
            *o = p;
        }
    }
}

// ---------------- host ----------------
extern "C" void kernel_launch(void* const* d_in, const int* in_sizes, int n_in,
                              void* d_out, int out_size, void* d_ws, size_t ws_size,
                              hipStream_t stream)
{
    const float* x   = (const float*)d_in[0];
    const float* W0  = (const float*)d_in[1];
    const float* b0  = (const float*)d_in[2];
    const float* W1  = (const float*)d_in[3];
    const float* b1  = (const float*)d_in[4];
    const float* lng = (const float*)d_in[5];
    const float* lnb = (const float*)d_in[6];
    const float* W2  = (const float*)d_in[7];
    const float* b2  = (const float*)d_in[8];
    const float* Wg1 = (const float*)d_in[9];
    const float* bg1 = (const float*)d_in[10];
    const float* Wg2 = (const float*)d_in[11];
    const float* bg2 = (const float*)d_in[12];
    float* out = (float*)d_out;

    const int B = 8192, D = 1024, H = 1024, E = 8, G = 256;

    char* ws = (char*)d_ws;
    ushort* x_bf  = (ushort*)ws;  ws += (size_t)B * D * 2;
    ushort* w0_bf = (ushort*)ws;  ws += (size_t)E * H * D * 2;
    ushort* w1_bf = (ushort*)ws;  ws += (size_t)E * H * H * 2;
    ushort* w2_bf = (ushort*)ws;  ws += (size_t)E * D * H * 2;
    ushort* wg1bf = (ushort*)ws;  ws += (size_t)G * D * 2;
    ushort* gh_bf = (ushort*)ws;  ws += (size_t)B * G * 2;
    float*  gatep = (float*)ws;   ws += (size_t)B * E * 4;

    size_t used  = (size_t)(ws - (char*)d_ws);
    size_t avail = (ws_size > used) ? ws_size - used : 0;
    size_t per_eg = (size_t)B * H * 2 * 2;   // h-buf + z-buf per expert
    int EG = 1;
    for (int cand = 8; cand >= 1; cand >>= 1)
        if ((size_t)cand * per_eg <= avail) { EG = cand; break; }

    ushort* hbuf = (ushort*)ws;
    ushort* zbuf = (ushort*)(ws + (size_t)EG * B * H * 2);

    auto cvt = [&](const float* src, ushort* dst, size_t n) {
        int n4 = (int)(n / 4);
        int blocks = (n4 + 255) / 256;
        if (blocks > 2048) blocks = 2048;
        cvt_kernel<<<dim3(blocks), dim3(256), 0, stream>>>(src, dst, n4);
    };
    cvt(x,   x_bf,  (size_t)B * D);
    cvt(W0,  w0_bf, (size_t)E * H * D);
    cvt(W1,  w1_bf, (size_t)E * H * H);
    cvt(W2,  w2_bf, (size_t)E * D * H);
    cvt(Wg1, wg1bf, (size_t)G * D);

    // gate
    gemm_bt<0><<<dim3(B / 128, G / 128), dim3(256), 0, stream>>>(
        x_bf, wg1bf, bg1, gh_bf, B, G, D);
    gate2_kernel<<<dim3(B / 4), dim3(256), 0, stream>>>(gh_bf, Wg2, bg2, gatep);

    const int cb4 = 2048;
    for (int e0 = 0; e0 < E; e0 += EG) {
        const int eg = (E - e0 < EG) ? (E - e0) : EG;
        // layer0: h = relu(x @ W0[e]^T + b0[e])
        gemm256<0><<<dim3(B / 256, H / 256, eg), dim3(512), 0, stream>>>(
            x_bf, w0_bf + (size_t)e0 * H * D, b0 + (size_t)e0 * H, hbuf,
            B, H, D, 0, (long)H * D, H, (long)B * H);
        // layer1: z = h @ W1[e]^T + b1[e]
        gemm256<1><<<dim3(B / 256, H / 256, eg), dim3(512), 0, stream>>>(
            hbuf, w1_bf + (size_t)e0 * H * H, b1 + (size_t)e0 * H, zbuf,
            B, H, H, (long)B * H, (long)H * H, H, (long)B * H);
        // LN -> relu -> +h
        ln_kernel<<<dim3(B, eg), dim3(256), 0, stream>>>(
            zbuf, hbuf, lng + (size_t)e0 * H, lnb + (size_t)e0 * H, B, H);
        // layer2: eo = hp @ W2[e]^T + b2[e]  (into hbuf)
        gemm256<1><<<dim3(B / 256, D / 256, eg), dim3(512), 0, stream>>>(
            zbuf, w2_bf + (size_t)e0 * D * H, b2 + (size_t)e0 * D, hbuf,
            B, D, H, (long)B * H, (long)D * H, D, (long)B * D);
        // gated combine
        combine_kernel<<<dim3(cb4), dim3(256), 0, stream>>>(
            hbuf, gatep, out, B * (D / 4), e0, eg, (e0 == 0) ? 1 : 0);
    }
}